// Round 3
// baseline (108.048 us; speedup 1.0000x reference)
//
#include <hip/hip_runtime.h>

// Degrade: per-sample depthwise 13x13 cross-correlation, stride 4,
// replicate padding p=6.  im: [8,4,1024,1024] f32, kernel: [8,1,13,13] f32,
// out: [8,4,256,256] f32.
//
// R2: occupancy fix.  4 outputs/thread (4 wide x 1 tall) -> 512K threads =
// 8192 waves = 100% occupancy potential (R1's 8/thread capped at 50%).
// Row loop is exactly 13 iterations, no ky conditionals, fully unrolled so
// the scheduler hoists float4 gathers across rows.  Vertical reuse moves
// from registers to L2 (~3.25x row re-read = ~420 MB @ 34.5 TB/s ~ 12 us,
// under the 26 us HBM floor).

#define KS 13
#define PAD 6
#define STR 4
#define IH 1024
#define IW 1024
#define OH 256
#define OW 256
#define SPAN 28       // aligned float window per input row (7 x float4)

__global__ __launch_bounds__(256) void degrade_kernel(
    const float* __restrict__ im,
    const float* __restrict__ kern,
    float* __restrict__ out)
{
    const int plane = blockIdx.z;       // b*4 + c
    const int b     = plane >> 2;
    const int tid   = threadIdx.x;
    const int tx    = tid & 7;          // 8 threads across x (4 outputs each)
    const int ty    = tid >> 3;         // 32 threads across y (1 output each)
    const int OX0   = blockIdx.x * 32;
    const int OY0   = blockIdx.y * 32;

    // kernel weights, rows padded to 16 floats for aligned b128 reads
    __shared__ float sk[KS][16];
    if (tid < KS * 16) {
        int r = tid >> 4, c = tid & 15;
        sk[r][c] = (c < KS) ? kern[b * KS * KS + r * KS + c] : 0.0f;
    }
    __syncthreads();

    const float* __restrict__ pl = im + (size_t)plane * (IH * IW);

    // aligned window start (gx0 = 4*OX0+16*tx-6 === 2 mod 4 -> back up 2)
    const int abase     = 4 * OX0 + 16 * tx - 8;
    const bool interior = (abase >= 0) && (abase + SPAN <= IW);
    const int gy0       = (OY0 + ty) * STR - PAD;

    float acc0 = 0.f, acc1 = 0.f, acc2 = 0.f, acc3 = 0.f;

#pragma unroll
    for (int ky = 0; ky < KS; ++ky) {
        const int gy = min(max(gy0 + ky, 0), IH - 1);
        const float* __restrict__ row = pl + (size_t)gy * IW;

        float v[SPAN];
        if (interior) {
            const float4* __restrict__ rp = (const float4*)(row + abase);
#pragma unroll
            for (int q = 0; q < SPAN / 4; ++q) {
                float4 x = rp[q];
                v[4 * q + 0] = x.x; v[4 * q + 1] = x.y;
                v[4 * q + 2] = x.z; v[4 * q + 3] = x.w;
            }
        } else {
#pragma unroll
            for (int u = 0; u < SPAN; ++u)
                v[u] = row[min(max(abase + u, 0), IW - 1)];
        }

        float4 k0 = *(const float4*)&sk[ky][0];
        float4 k1 = *(const float4*)&sk[ky][4];
        float4 k2 = *(const float4*)&sk[ky][8];
        float4 k3 = *(const float4*)&sk[ky][12];
        float kr[KS] = {k0.x, k0.y, k0.z, k0.w,
                        k1.x, k1.y, k1.z, k1.w,
                        k2.x, k2.y, k2.z, k2.w, k3.x};
#pragma unroll
        for (int kx = 0; kx < KS; ++kx) {
            const float kv = kr[kx];
            acc0 = fmaf(v[2 + kx],      kv, acc0);
            acc1 = fmaf(v[6 + kx],      kv, acc1);
            acc2 = fmaf(v[10 + kx],     kv, acc2);
            acc3 = fmaf(v[14 + kx],     kv, acc3);
        }
    }

    const int oy = OY0 + ty;
    *(float4*)(out + ((size_t)plane * OH + oy) * OW + OX0 + 4 * tx) =
        make_float4(acc0, acc1, acc2, acc3);
}

extern "C" void kernel_launch(void* const* d_in, const int* in_sizes, int n_in,
                              void* d_out, int out_size, void* d_ws, size_t ws_size,
                              hipStream_t stream)
{
    const float* im   = (const float*)d_in[0];
    const float* kern = (const float*)d_in[1];
    float* out        = (float*)d_out;

    dim3 grid(OW / 32, OH / 32, 32);   // 8 x 8 x 32 = 2048 blocks
    degrade_kernel<<<grid, 256, 0, stream>>>(im, kern, out);
}

// Round 4
// 46.144 us; speedup vs baseline: 2.3415x; 2.3415x over previous
//
#include <hip/hip_runtime.h>

// Degrade: per-sample depthwise 13x13 cross-correlation, stride 4,
// replicate padding p=6.  im: [8,4,1024,1024] f32, kernel: [8,1,13,13] f32,
// out: [8,4,256,256] f32.
//
// R3: TA line-touch model (validated on R0/R1/R2: ~1 distinct-line touch
// per cycle per CU).  touches/output = (TW+3)(4*TH+9)/(TW*TH):
//   R1 (4,2)=14.9 -> 50us pred/56 obs.  This round (4,4)=10.9 -> ~36us.
// Structure = R0's runtime 25-row loop (VGPR-safe, 64 regs) + R1's aligned
// float4 row loads (abase === 2 mod 4 at compile time).  Row loop must NOT
// fully unroll (R2 lesson: 256 VGPR -> occupancy collapse).

#define KS 13
#define PAD 6
#define STR 4
#define IH 1024
#define IW 1024
#define OH 256
#define OW 256
#define SPAN 28       // aligned float window per input row (7 x float4)

__global__ __launch_bounds__(256) void degrade_kernel(
    const float* __restrict__ im,
    const float* __restrict__ kern,
    float* __restrict__ out)
{
    const int plane = blockIdx.z;       // b*4 + c
    const int b     = plane >> 2;
    const int tid   = threadIdx.x;
    const int tx    = tid & 15;         // 16 threads across x (4 outputs each)
    const int ty    = tid >> 4;         // 16 threads across y (4 outputs each)
    const int OX0   = blockIdx.x * 64;
    const int OY0   = blockIdx.y * 64;

    // kernel weights, rows padded to 16 floats for aligned b128 reads
    __shared__ float sk[KS][16];
    if (tid < KS * 16) {
        int r = tid >> 4, c = tid & 15;
        sk[r][c] = (c < KS) ? kern[b * KS * KS + r * KS + c] : 0.0f;
    }
    __syncthreads();

    const float* __restrict__ pl = im + (size_t)plane * (IH * IW);

    // aligned window start (gx0 = 4*(OX0+4*tx)-6 === 2 mod 4 -> back up 2)
    const int abase     = 4 * OX0 + 16 * tx - 8;
    const bool interior = (abase >= 0) && (abase + SPAN <= IW);
    const int gy0       = (OY0 + 4 * ty) * STR - PAD;

    float acc[4][4];
#pragma unroll
    for (int j = 0; j < 4; ++j)
#pragma unroll
        for (int i = 0; i < 4; ++i) acc[j][i] = 0.0f;

    // 25 input rows feed this thread's 4 output rows; runtime loop (do NOT
    // fully unroll -- register pressure).  t = 4*j + ky.
#pragma unroll 1
    for (int t = 0; t < 25; ++t) {
        const int gy = min(max(gy0 + t, 0), IH - 1);
        const float* __restrict__ row = pl + (size_t)gy * IW;

        float v[SPAN];
        if (interior) {
            const float4* __restrict__ rp = (const float4*)(row + abase);
#pragma unroll
            for (int q = 0; q < SPAN / 4; ++q) {
                float4 x = rp[q];
                v[4 * q + 0] = x.x; v[4 * q + 1] = x.y;
                v[4 * q + 2] = x.z; v[4 * q + 3] = x.w;
            }
        } else {
#pragma unroll
            for (int u = 0; u < SPAN; ++u)
                v[u] = row[min(max(abase + u, 0), IW - 1)];
        }

#pragma unroll
        for (int j = 0; j < 4; ++j) {
            const int ky = t - STR * j;
            if (ky >= 0 && ky < KS) {           // wave-uniform branch
                float4 k0 = *(const float4*)&sk[ky][0];
                float4 k1 = *(const float4*)&sk[ky][4];
                float4 k2 = *(const float4*)&sk[ky][8];
                float4 k3 = *(const float4*)&sk[ky][12];
                float kr[KS] = {k0.x, k0.y, k0.z, k0.w,
                                k1.x, k1.y, k1.z, k1.w,
                                k2.x, k2.y, k2.z, k2.w, k3.x};
#pragma unroll
                for (int kx = 0; kx < KS; ++kx) {
                    const float kv = kr[kx];
#pragma unroll
                    for (int i = 0; i < 4; ++i)
                        acc[j][i] = fmaf(v[2 + 4 * i + kx], kv, acc[j][i]);
                }
            }
        }
    }

#pragma unroll
    for (int j = 0; j < 4; ++j) {
        const int oy = OY0 + 4 * ty + j;
        *(float4*)(out + ((size_t)plane * OH + oy) * OW + OX0 + 4 * tx) =
            make_float4(acc[j][0], acc[j][1], acc[j][2], acc[j][3]);
    }
}

extern "C" void kernel_launch(void* const* d_in, const int* in_sizes, int n_in,
                              void* d_out, int out_size, void* d_ws, size_t ws_size,
                              hipStream_t stream)
{
    const float* im   = (const float*)d_in[0];
    const float* kern = (const float*)d_in[1];
    float* out        = (float*)d_out;

    dim3 grid(OW / 64, OH / 64, 32);   // 4 x 4 x 32 = 512 blocks
    degrade_kernel<<<grid, 256, 0, stream>>>(im, kern, out);
}